// Round 6
// baseline (2378.451 us; speedup 1.0000x reference)
//
#include <hip/hip_runtime.h>
#include <math.h>

#define NLVL  16
#define TSZ   (1u << 19)
#define TMASK (TSZ - 1u)

struct ResArr { int m1[NLVL * 4]; };  // per level, per dim: res-1

// ---------------------------------------------------------------------------
// Encode: EXACT round-4 kernel (830 us, FETCH 0.72 GB, L2-request-bound).
// Round-5's float4 corner-pair variant REGRESSED (2.5 vs 1.9 cyc/lane-req):
// gather cost scales with request width, keep 8 B dwordx2 gathers.
// Level-major grid keeps each XCD's L2 resident on one 4 MB level table.
// ---------------------------------------------------------------------------
__global__ __launch_bounds__(256, 4)
void ingp_encode(const float4* __restrict__ x,
                 const float2* __restrict__ table,
                 float2*       __restrict__ feat,   // [NLVL][N] level-major
                 int N, int chunksPerLevel, ResArr res)
{
    const int l     = blockIdx.x / chunksPerLevel;
    const int chunk = blockIdx.x - l * chunksPerLevel;
    const int n     = chunk * 256 + threadIdx.x;
    if (n >= N) return;

    const float4 xv = x[n];
    const float px[4] = {xv.x, xv.y, xv.z, xv.w};

    int   rm[4], bi[4];
    float fr[4], om[4];
    #pragma unroll
    for (int d = 0; d < 4; ++d) {
        const int r = res.m1[l * 4 + d];       // wave-uniform -> scalar
        rm[d] = r;
        const float pos = px[d] * (float)r;
        const float fb  = floorf(pos);
        fr[d] = pos - fb;
        om[d] = 1.0f - fr[d];
        bi[d] = (int)fb;
    }
    const float2* tl = table + (size_t)l * TSZ;

    float2 fv[16];
    float  wt[16];
    #pragma unroll
    for (int c = 0; c < 16; ++c) {
        int c0 = bi[0] + ( c       & 1);
        int c1 = bi[1] + ((c >> 1) & 1);
        int c2 = bi[2] + ((c >> 2) & 1);
        int c3 = bi[3] + ((c >> 3) & 1);
        c0 = min(max(c0, 0), rm[0]);
        c1 = min(max(c1, 0), rm[1]);
        c2 = min(max(c2, 0), rm[2]);
        c3 = min(max(c3, 0), rm[3]);
        const unsigned hh = (unsigned)c0
                          ^ ((unsigned)c1 * 2654435761u)
                          ^ ((unsigned)c2 * 805459861u)
                          ^ ((unsigned)c3 * 3674653429u);
        fv[c] = tl[hh & TMASK];
        float w = ( c       & 1) ? fr[0] : om[0];
        w      *= ((c >> 1) & 1) ? fr[1] : om[1];
        w      *= ((c >> 2) & 1) ? fr[2] : om[2];
        w      *= ((c >> 3) & 1) ? fr[3] : om[3];
        wt[c] = w;
    }

    float a0 = 0.0f, a1 = 0.0f;
    #pragma unroll
    for (int c = 0; c < 16; ++c) {           // same order as reference einsum
        a0 = fmaf(wt[c], fv[c].x, a0);
        a1 = fmaf(wt[c], fv[c].y, a1);
    }
    feat[(size_t)l * N + n] = make_float2(a0, a1);
}

// ---------------------------------------------------------------------------
// MLP: TWO points per thread, plain scalar fmaf. Each weight s_load is shared
// by the two points' FMAs (both read the same SGPR -> legal, zero movs).
// Halves s_load traffic and i-fetch PER POINT (round-4 MLP ran ~6x above the
// FMA-issue floor; theory: wave-count-scaled overheads). h3 is streamed into
// the w_out fold (never stored) to cap live regs ~270; launch_bounds(256,1)
// -> 512 VGPR budget, no spill. Per-point FMA order identical -> absmax 0.0.
// ---------------------------------------------------------------------------
__global__ __launch_bounds__(256, 1)
void ingp_mlp2(const float2* __restrict__ feat,   // [NLVL][N]
               const float*  __restrict__ w0,
               const float*  __restrict__ w1,
               const float*  __restrict__ w2,
               const float*  __restrict__ wout,
               const float*  __restrict__ bout,
               float*        __restrict__ out,
               int N)
{
    const int t  = blockIdx.x * blockDim.x + threadIdx.x;
    const int n0 = 2 * t;
    const int n1 = 2 * t + 1;
    if (n0 >= N) return;

    // Feats for both points: adjacent float2 pairs -> one float4 per level.
    float2 fA[NLVL], fB[NLVL];
    #pragma unroll
    for (int l = 0; l < NLVL; ++l) {
        const float4 q = *(const float4*)(feat + (size_t)l * N + n0);
        fA[l] = make_float2(q.x, q.y);
        fB[l] = make_float2(q.z, q.w);
    }

    float a1[64], b1[64];
    #pragma unroll
    for (int j = 0; j < 64; ++j) { a1[j] = 0.0f; b1[j] = 0.0f; }
    #pragma unroll
    for (int l = 0; l < NLVL; ++l) {
        #pragma unroll
        for (int j = 0; j < 64; ++j) {
            const float wlo = w0[j * 32 + 2 * l];
            const float whi = w0[j * 32 + 2 * l + 1];
            a1[j] = fmaf(wlo, fA[l].x, fmaf(whi, fA[l].y, a1[j]));
            b1[j] = fmaf(wlo, fB[l].x, fmaf(whi, fB[l].y, b1[j]));
        }
    }
    #pragma unroll
    for (int j = 0; j < 64; ++j) {
        a1[j] = fmaxf(a1[j], 0.0f);
        b1[j] = fmaxf(b1[j], 0.0f);
    }

    float a2[64], b2[64];
    #pragma unroll
    for (int j = 0; j < 64; ++j) {
        float accA = 0.0f, accB = 0.0f;
        const float* wr = w1 + j * 64;
        #pragma unroll
        for (int i = 0; i < 64; ++i) {
            const float wv = wr[i];
            accA = fmaf(wv, a1[i], accA);
            accB = fmaf(wv, b1[i], accB);
        }
        a2[j] = fmaxf(accA, 0.0f);
        b2[j] = fmaxf(accB, 0.0f);
    }

    // Layer 2 streamed: finalize each h3 neuron, fold into out immediately.
    float oA[3], oB[3];
    #pragma unroll
    for (int k = 0; k < 3; ++k) { oA[k] = bout[k]; oB[k] = bout[k]; }
    #pragma unroll
    for (int j = 0; j < 64; ++j) {
        float accA = 0.0f, accB = 0.0f;
        const float* wr = w2 + j * 64;
        #pragma unroll
        for (int i = 0; i < 64; ++i) {
            const float wv = wr[i];
            accA = fmaf(wv, a2[i], accA);
            accB = fmaf(wv, b2[i], accB);
        }
        const float hA = fmaxf(accA, 0.0f);
        const float hB = fmaxf(accB, 0.0f);
        #pragma unroll
        for (int k = 0; k < 3; ++k) {
            const float wv = wout[k * 64 + j];
            oA[k] = fmaf(wv, hA, oA[k]);
            oB[k] = fmaf(wv, hB, oB[k]);
        }
    }
    #pragma unroll
    for (int k = 0; k < 3; ++k) out[n0 * 3 + k] = oA[k];
    if (n1 < N) {
        #pragma unroll
        for (int k = 0; k < 3; ++k) out[n1 * 3 + k] = oB[k];
    }
}

// ---------------------------------------------------------------------------
// Fallback: round-2 fused kernel (used only if ws is too small for features).
// ---------------------------------------------------------------------------
__global__ __launch_bounds__(256, 2)
void ingp_fused(const float4* __restrict__ x,
                const float2* __restrict__ table,
                const float*  __restrict__ w0,
                const float*  __restrict__ w1,
                const float*  __restrict__ w2,
                const float*  __restrict__ wout,
                const float*  __restrict__ bout,
                float*        __restrict__ out,
                int N, ResArr res)
{
    const int n = blockIdx.x * blockDim.x + threadIdx.x;
    if (n >= N) return;

    const float4 xv = x[n];
    const float px[4] = {xv.x, xv.y, xv.z, xv.w};

    float h1[64];
    #pragma unroll
    for (int j = 0; j < 64; ++j) h1[j] = 0.0f;

    float a0p = 0.0f, a1p = 0.0f;

    #pragma unroll 1
    for (int l = 0; l < NLVL; ++l) {
        int   rm[4], bi[4];
        float fr[4], om[4];
        #pragma unroll
        for (int d = 0; d < 4; ++d) {
            const int r = res.m1[l * 4 + d];
            rm[d] = r;
            const float pos = px[d] * (float)r;
            const float fb  = floorf(pos);
            fr[d] = pos - fb;
            om[d] = 1.0f - fr[d];
            bi[d] = (int)fb;
        }
        const float2* tl = table + (size_t)l * TSZ;

        float2 fv[16];
        float  wt[16];
        #pragma unroll
        for (int c = 0; c < 16; ++c) {
            int c0 = bi[0] + ( c       & 1);
            int c1 = bi[1] + ((c >> 1) & 1);
            int c2 = bi[2] + ((c >> 2) & 1);
            int c3 = bi[3] + ((c >> 3) & 1);
            c0 = min(max(c0, 0), rm[0]);
            c1 = min(max(c1, 0), rm[1]);
            c2 = min(max(c2, 0), rm[2]);
            c3 = min(max(c3, 0), rm[3]);
            const unsigned hh = (unsigned)c0
                              ^ ((unsigned)c1 * 2654435761u)
                              ^ ((unsigned)c2 * 805459861u)
                              ^ ((unsigned)c3 * 3674653429u);
            fv[c] = tl[hh & TMASK];
            float w = ( c       & 1) ? fr[0] : om[0];
            w      *= ((c >> 1) & 1) ? fr[1] : om[1];
            w      *= ((c >> 2) & 1) ? fr[2] : om[2];
            w      *= ((c >> 3) & 1) ? fr[3] : om[3];
            wt[c] = w;
        }
        {
            const int lp = (l == 0) ? 0 : (l - 1);
            const float* w0c = w0 + 2 * lp;
            #pragma unroll
            for (int j = 0; j < 64; ++j)
                h1[j] = fmaf(w0c[j * 32], a0p, fmaf(w0c[j * 32 + 1], a1p, h1[j]));
        }
        float a0 = 0.0f, a1 = 0.0f;
        #pragma unroll
        for (int c = 0; c < 16; ++c) {
            a0 = fmaf(wt[c], fv[c].x, a0);
            a1 = fmaf(wt[c], fv[c].y, a1);
        }
        a0p = a0; a1p = a1;
    }
    {
        const float* w0c = w0 + 2 * (NLVL - 1);
        #pragma unroll
        for (int j = 0; j < 64; ++j)
            h1[j] = fmaf(w0c[j * 32], a0p, fmaf(w0c[j * 32 + 1], a1p, h1[j]));
    }
    #pragma unroll
    for (int j = 0; j < 64; ++j) h1[j] = fmaxf(h1[j], 0.0f);

    float h2[64];
    #pragma unroll
    for (int j = 0; j < 64; ++j) {
        float acc = 0.0f;
        const float* wr = w1 + j * 64;
        #pragma unroll
        for (int i = 0; i < 64; ++i) acc = fmaf(wr[i], h1[i], acc);
        h2[j] = fmaxf(acc, 0.0f);
    }
    float h3[64];
    #pragma unroll
    for (int j = 0; j < 64; ++j) {
        float acc = 0.0f;
        const float* wr = w2 + j * 64;
        #pragma unroll
        for (int i = 0; i < 64; ++i) acc = fmaf(wr[i], h2[i], acc);
        h3[j] = fmaxf(acc, 0.0f);
    }
    float o[3];
    #pragma unroll
    for (int k = 0; k < 3; ++k) {
        float acc = bout[k];
        const float* wr = wout + k * 64;
        #pragma unroll
        for (int i = 0; i < 64; ++i) acc = fmaf(wr[i], h3[i], acc);
        o[k] = acc;
    }
    out[n * 3 + 0] = o[0];
    out[n * 3 + 1] = o[1];
    out[n * 3 + 2] = o[2];
}

extern "C" void kernel_launch(void* const* d_in, const int* in_sizes, int n_in,
                              void* d_out, int out_size, void* d_ws, size_t ws_size,
                              hipStream_t stream) {
    (void)n_in; (void)out_size;

    const float* x     = (const float*)d_in[0];
    const float* table = (const float*)d_in[1];
    const float* w0    = (const float*)d_in[2];
    const float* w1    = (const float*)d_in[3];
    const float* w2    = (const float*)d_in[4];
    const float* wout  = (const float*)d_in[5];
    const float* bout  = (const float*)d_in[6];
    float* out = (float*)d_out;

    const int N = in_sizes[0] / 4;

    // Replicate numpy's float64 resolution computation bit-for-bit (same
    // glibc pow). Levels 5/10/15 of dim 3 sit on exact integer boundaries
    // (8^(5/15)==2), so floor() must see the same double as numpy produced.
    ResArr res;
    for (int d = 0; d < 4; ++d) {
        const double minr = 16.0;
        const double maxr = (d == 3) ? 128.0 : 256.0;
        const double growth = pow(maxr / minr, 1.0 / (double)(NLVL - 1));
        for (int l = 0; l < NLVL; ++l) {
            const int r = (int)floor(minr * pow(growth, (double)l));
            res.m1[l * 4 + d] = r - 1;
        }
    }

    const size_t featBytes = (size_t)NLVL * (size_t)N * sizeof(float2);

    if (ws_size >= featBytes) {
        float2* feat = (float2*)d_ws;
        const int chunksPerLevel = (N + 255) / 256;
        dim3 eg(NLVL * chunksPerLevel), eb(256);
        hipLaunchKernelGGL(ingp_encode, eg, eb, 0, stream,
                           (const float4*)x, (const float2*)table, feat,
                           N, chunksPerLevel, res);
        const int nThreads = (N + 1) / 2;
        dim3 mg((nThreads + 255) / 256), mb(256);
        hipLaunchKernelGGL(ingp_mlp2, mg, mb, 0, stream,
                           feat, w0, w1, w2, wout, bout, out, N);
    } else {
        dim3 grid((N + 255) / 256), block(256);
        hipLaunchKernelGGL(ingp_fused, grid, block, 0, stream,
                           (const float4*)x, (const float2*)table,
                           w0, w1, w2, wout, bout, out, N, res);
    }
}

// Round 7
// 1447.068 us; speedup vs baseline: 1.6436x; 1.6436x over previous
//
#include <hip/hip_runtime.h>
#include <math.h>

#define NLVL  16
#define TSZ   (1u << 19)
#define TMASK (TSZ - 1u)

struct ResArr { int m1[NLVL * 4]; };  // per level, per dim: res-1

static __device__ __forceinline__ unsigned f2bf_rne(float f) {
    unsigned u = __float_as_uint(f);
    return (u + 0x7fffu + ((u >> 16) & 1u)) >> 16;   // round-to-nearest-even
}

// ---------------------------------------------------------------------------
// Table fp32->bf16 pack: entry (float2) -> one dword (lo=bf16(f0), hi=bf16(f1)).
// 8.4M entries, streamed; ~20 us. Runs every launch (ws is re-poisoned).
// ---------------------------------------------------------------------------
__global__ __launch_bounds__(256)
void cvt_table(const float4* __restrict__ t, uint2* __restrict__ bt, int nPairs)
{
    const int i = blockIdx.x * 256 + threadIdx.x;   // 2 entries per thread
    if (i >= nPairs) return;
    const float4 v = t[i];
    uint2 o;
    o.x = f2bf_rne(v.x) | (f2bf_rne(v.y) << 16);
    o.y = f2bf_rne(v.z) | (f2bf_rne(v.w) << 16);
    bt[i] = o;
}

// ---------------------------------------------------------------------------
// Encode (bf16 table): round-4 structure (830 us, L2-request-bound at 1.9
// cyc/lane-request), but gathers are 4 B dwords instead of 8 B. Round-5
// measured request cost scaling with width (8B=1.9, 16B=2.5 cyc) -> predict
// ~1.6 cyc at 4 B. Level-major grid keeps each XCD's L2 on one level table
// (now 2 MB). bf16->fp32 expansion is exact; FMA order unchanged.
// ---------------------------------------------------------------------------
__global__ __launch_bounds__(256, 4)
void ingp_encode_bf(const float4*   __restrict__ x,
                    const unsigned* __restrict__ btable,
                    float2*         __restrict__ feat,   // [NLVL][N]
                    int N, int chunksPerLevel, ResArr res)
{
    const int l     = blockIdx.x / chunksPerLevel;
    const int chunk = blockIdx.x - l * chunksPerLevel;
    const int n     = chunk * 256 + threadIdx.x;
    if (n >= N) return;

    const float4 xv = x[n];
    const float px[4] = {xv.x, xv.y, xv.z, xv.w};

    int   rm[4], bi[4];
    float fr[4], om[4];
    #pragma unroll
    for (int d = 0; d < 4; ++d) {
        const int r = res.m1[l * 4 + d];       // wave-uniform -> scalar
        rm[d] = r;
        const float pos = px[d] * (float)r;
        const float fb  = floorf(pos);
        fr[d] = pos - fb;
        om[d] = 1.0f - fr[d];
        bi[d] = (int)fb;
    }
    const unsigned* tl = btable + (size_t)l * TSZ;

    unsigned gv[16];
    float    wt[16];
    #pragma unroll
    for (int c = 0; c < 16; ++c) {
        int c0 = bi[0] + ( c       & 1);
        int c1 = bi[1] + ((c >> 1) & 1);
        int c2 = bi[2] + ((c >> 2) & 1);
        int c3 = bi[3] + ((c >> 3) & 1);
        c0 = min(max(c0, 0), rm[0]);
        c1 = min(max(c1, 0), rm[1]);
        c2 = min(max(c2, 0), rm[2]);
        c3 = min(max(c3, 0), rm[3]);
        const unsigned hh = (unsigned)c0
                          ^ ((unsigned)c1 * 2654435761u)
                          ^ ((unsigned)c2 * 805459861u)
                          ^ ((unsigned)c3 * 3674653429u);
        gv[c] = tl[hh & TMASK];                 // 4 B gather
        float w = ( c       & 1) ? fr[0] : om[0];
        w      *= ((c >> 1) & 1) ? fr[1] : om[1];
        w      *= ((c >> 2) & 1) ? fr[2] : om[2];
        w      *= ((c >> 3) & 1) ? fr[3] : om[3];
        wt[c] = w;
    }

    float a0 = 0.0f, a1 = 0.0f;
    #pragma unroll
    for (int c = 0; c < 16; ++c) {             // same order as reference einsum
        const float fx = __uint_as_float(gv[c] << 16);          // feature 0
        const float fy = __uint_as_float(gv[c] & 0xffff0000u);  // feature 1
        a0 = fmaf(wt[c], fx, a0);
        a1 = fmaf(wt[c], fy, a1);
    }
    feat[(size_t)l * N + n] = make_float2(a0, a1);
}

// ---------------------------------------------------------------------------
// Encode (fp32 table): EXACT round-4 kernel — fallback when ws can't hold the
// bf16 table.
// ---------------------------------------------------------------------------
__global__ __launch_bounds__(256, 4)
void ingp_encode(const float4* __restrict__ x,
                 const float2* __restrict__ table,
                 float2*       __restrict__ feat,
                 int N, int chunksPerLevel, ResArr res)
{
    const int l     = blockIdx.x / chunksPerLevel;
    const int chunk = blockIdx.x - l * chunksPerLevel;
    const int n     = chunk * 256 + threadIdx.x;
    if (n >= N) return;

    const float4 xv = x[n];
    const float px[4] = {xv.x, xv.y, xv.z, xv.w};

    int   rm[4], bi[4];
    float fr[4], om[4];
    #pragma unroll
    for (int d = 0; d < 4; ++d) {
        const int r = res.m1[l * 4 + d];
        rm[d] = r;
        const float pos = px[d] * (float)r;
        const float fb  = floorf(pos);
        fr[d] = pos - fb;
        om[d] = 1.0f - fr[d];
        bi[d] = (int)fb;
    }
    const float2* tl = table + (size_t)l * TSZ;

    float2 fv[16];
    float  wt[16];
    #pragma unroll
    for (int c = 0; c < 16; ++c) {
        int c0 = bi[0] + ( c       & 1);
        int c1 = bi[1] + ((c >> 1) & 1);
        int c2 = bi[2] + ((c >> 2) & 1);
        int c3 = bi[3] + ((c >> 3) & 1);
        c0 = min(max(c0, 0), rm[0]);
        c1 = min(max(c1, 0), rm[1]);
        c2 = min(max(c2, 0), rm[2]);
        c3 = min(max(c3, 0), rm[3]);
        const unsigned hh = (unsigned)c0
                          ^ ((unsigned)c1 * 2654435761u)
                          ^ ((unsigned)c2 * 805459861u)
                          ^ ((unsigned)c3 * 3674653429u);
        fv[c] = tl[hh & TMASK];
        float w = ( c       & 1) ? fr[0] : om[0];
        w      *= ((c >> 1) & 1) ? fr[1] : om[1];
        w      *= ((c >> 2) & 1) ? fr[2] : om[2];
        w      *= ((c >> 3) & 1) ? fr[3] : om[3];
        wt[c] = w;
    }

    float a0 = 0.0f, a1 = 0.0f;
    #pragma unroll
    for (int c = 0; c < 16; ++c) {
        a0 = fmaf(wt[c], fv[c].x, a0);
        a1 = fmaf(wt[c], fv[c].y, a1);
    }
    feat[(size_t)l * N + n] = make_float2(a0, a1);
}

// ---------------------------------------------------------------------------
// MLP: EXACT round-4 kernel (455 us). One point per thread, fully unrolled;
// weight reads wave-uniform -> s_load; VGPR ~170 -> ~3 waves/SIMD. Round-6's
// 2-points/thread variant REGRESSED 3.3x (VGPR 188, occupancy 12%): fp32 MLP
// is latency-hiding-bound, occupancy dominates per-point overhead.
// ---------------------------------------------------------------------------
__global__ __launch_bounds__(256, 2)
void ingp_mlp(const float2* __restrict__ feat,   // [NLVL][N]
              const float*  __restrict__ w0,
              const float*  __restrict__ w1,
              const float*  __restrict__ w2,
              const float*  __restrict__ wout,
              const float*  __restrict__ bout,
              float*        __restrict__ out,
              int N)
{
    const int n = blockIdx.x * blockDim.x + threadIdx.x;
    if (n >= N) return;

    float2 f[NLVL];
    #pragma unroll
    for (int l = 0; l < NLVL; ++l) f[l] = feat[(size_t)l * N + n];  // coalesced

    float h1[64];
    #pragma unroll
    for (int j = 0; j < 64; ++j) h1[j] = 0.0f;
    #pragma unroll
    for (int l = 0; l < NLVL; ++l) {
        #pragma unroll
        for (int j = 0; j < 64; ++j) {
            h1[j] = fmaf(w0[j * 32 + 2 * l], f[l].x,
                    fmaf(w0[j * 32 + 2 * l + 1], f[l].y, h1[j]));
        }
    }
    #pragma unroll
    for (int j = 0; j < 64; ++j) h1[j] = fmaxf(h1[j], 0.0f);

    float h2[64];
    #pragma unroll
    for (int j = 0; j < 64; ++j) {
        float acc = 0.0f;
        const float* wr = w1 + j * 64;
        #pragma unroll
        for (int i = 0; i < 64; ++i) acc = fmaf(wr[i], h1[i], acc);
        h2[j] = fmaxf(acc, 0.0f);
    }
    float h3[64];
    #pragma unroll
    for (int j = 0; j < 64; ++j) {
        float acc = 0.0f;
        const float* wr = w2 + j * 64;
        #pragma unroll
        for (int i = 0; i < 64; ++i) acc = fmaf(wr[i], h2[i], acc);
        h3[j] = fmaxf(acc, 0.0f);
    }
    float o[3];
    #pragma unroll
    for (int k = 0; k < 3; ++k) {
        float acc = bout[k];
        const float* wr = wout + k * 64;
        #pragma unroll
        for (int i = 0; i < 64; ++i) acc = fmaf(wr[i], h3[i], acc);
        o[k] = acc;
    }
    out[n * 3 + 0] = o[0];
    out[n * 3 + 1] = o[1];
    out[n * 3 + 2] = o[2];
}

// ---------------------------------------------------------------------------
// Fallback: round-2 fused kernel (used only if ws is too small for features).
// ---------------------------------------------------------------------------
__global__ __launch_bounds__(256, 2)
void ingp_fused(const float4* __restrict__ x,
                const float2* __restrict__ table,
                const float*  __restrict__ w0,
                const float*  __restrict__ w1,
                const float*  __restrict__ w2,
                const float*  __restrict__ wout,
                const float*  __restrict__ bout,
                float*        __restrict__ out,
                int N, ResArr res)
{
    const int n = blockIdx.x * blockDim.x + threadIdx.x;
    if (n >= N) return;

    const float4 xv = x[n];
    const float px[4] = {xv.x, xv.y, xv.z, xv.w};

    float h1[64];
    #pragma unroll
    for (int j = 0; j < 64; ++j) h1[j] = 0.0f;

    float a0p = 0.0f, a1p = 0.0f;

    #pragma unroll 1
    for (int l = 0; l < NLVL; ++l) {
        int   rm[4], bi[4];
        float fr[4], om[4];
        #pragma unroll
        for (int d = 0; d < 4; ++d) {
            const int r = res.m1[l * 4 + d];
            rm[d] = r;
            const float pos = px[d] * (float)r;
            const float fb  = floorf(pos);
            fr[d] = pos - fb;
            om[d] = 1.0f - fr[d];
            bi[d] = (int)fb;
        }
        const float2* tl = table + (size_t)l * TSZ;

        float2 fv[16];
        float  wt[16];
        #pragma unroll
        for (int c = 0; c < 16; ++c) {
            int c0 = bi[0] + ( c       & 1);
            int c1 = bi[1] + ((c >> 1) & 1);
            int c2 = bi[2] + ((c >> 2) & 1);
            int c3 = bi[3] + ((c >> 3) & 1);
            c0 = min(max(c0, 0), rm[0]);
            c1 = min(max(c1, 0), rm[1]);
            c2 = min(max(c2, 0), rm[2]);
            c3 = min(max(c3, 0), rm[3]);
            const unsigned hh = (unsigned)c0
                              ^ ((unsigned)c1 * 2654435761u)
                              ^ ((unsigned)c2 * 805459861u)
                              ^ ((unsigned)c3 * 3674653429u);
            fv[c] = tl[hh & TMASK];
            float w = ( c       & 1) ? fr[0] : om[0];
            w      *= ((c >> 1) & 1) ? fr[1] : om[1];
            w      *= ((c >> 2) & 1) ? fr[2] : om[2];
            w      *= ((c >> 3) & 1) ? fr[3] : om[3];
            wt[c] = w;
        }
        {
            const int lp = (l == 0) ? 0 : (l - 1);
            const float* w0c = w0 + 2 * lp;
            #pragma unroll
            for (int j = 0; j < 64; ++j)
                h1[j] = fmaf(w0c[j * 32], a0p, fmaf(w0c[j * 32 + 1], a1p, h1[j]));
        }
        float a0 = 0.0f, a1 = 0.0f;
        #pragma unroll
        for (int c = 0; c < 16; ++c) {
            a0 = fmaf(wt[c], fv[c].x, a0);
            a1 = fmaf(wt[c], fv[c].y, a1);
        }
        a0p = a0; a1p = a1;
    }
    {
        const float* w0c = w0 + 2 * (NLVL - 1);
        #pragma unroll
        for (int j = 0; j < 64; ++j)
            h1[j] = fmaf(w0c[j * 32], a0p, fmaf(w0c[j * 32 + 1], a1p, h1[j]));
    }
    #pragma unroll
    for (int j = 0; j < 64; ++j) h1[j] = fmaxf(h1[j], 0.0f);

    float h2[64];
    #pragma unroll
    for (int j = 0; j < 64; ++j) {
        float acc = 0.0f;
        const float* wr = w1 + j * 64;
        #pragma unroll
        for (int i = 0; i < 64; ++i) acc = fmaf(wr[i], h1[i], acc);
        h2[j] = fmaxf(acc, 0.0f);
    }
    float h3[64];
    #pragma unroll
    for (int j = 0; j < 64; ++j) {
        float acc = 0.0f;
        const float* wr = w2 + j * 64;
        #pragma unroll
        for (int i = 0; i < 64; ++i) acc = fmaf(wr[i], h2[i], acc);
        h3[j] = fmaxf(acc, 0.0f);
    }
    float o[3];
    #pragma unroll
    for (int k = 0; k < 3; ++k) {
        float acc = bout[k];
        const float* wr = wout + k * 64;
        #pragma unroll
        for (int i = 0; i < 64; ++i) acc = fmaf(wr[i], h3[i], acc);
        o[k] = acc;
    }
    out[n * 3 + 0] = o[0];
    out[n * 3 + 1] = o[1];
    out[n * 3 + 2] = o[2];
}

extern "C" void kernel_launch(void* const* d_in, const int* in_sizes, int n_in,
                              void* d_out, int out_size, void* d_ws, size_t ws_size,
                              hipStream_t stream) {
    (void)n_in; (void)out_size;

    const float* x     = (const float*)d_in[0];
    const float* table = (const float*)d_in[1];
    const float* w0    = (const float*)d_in[2];
    const float* w1    = (const float*)d_in[3];
    const float* w2    = (const float*)d_in[4];
    const float* wout  = (const float*)d_in[5];
    const float* bout  = (const float*)d_in[6];
    float* out = (float*)d_out;

    const int N = in_sizes[0] / 4;

    // Replicate numpy's float64 resolution computation bit-for-bit (same
    // glibc pow). Levels 5/10/15 of dim 3 sit on exact integer boundaries
    // (8^(5/15)==2), so floor() must see the same double as numpy produced.
    ResArr res;
    for (int d = 0; d < 4; ++d) {
        const double minr = 16.0;
        const double maxr = (d == 3) ? 128.0 : 256.0;
        const double growth = pow(maxr / minr, 1.0 / (double)(NLVL - 1));
        for (int l = 0; l < NLVL; ++l) {
            const int r = (int)floor(minr * pow(growth, (double)l));
            res.m1[l * 4 + d] = r - 1;
        }
    }

    const size_t featBytes = (size_t)NLVL * (size_t)N * sizeof(float2);
    const size_t btBytes   = (size_t)NLVL * (size_t)TSZ * sizeof(unsigned);
    const int chunksPerLevel = (N + 255) / 256;

    if (ws_size >= featBytes + btBytes) {
        float2*   feat = (float2*)d_ws;
        unsigned* bt   = (unsigned*)((char*)d_ws + featBytes);

        const int nPairs = (NLVL * TSZ) / 2;       // 2 entries per thread
        hipLaunchKernelGGL(cvt_table, dim3((nPairs + 255) / 256), dim3(256),
                           0, stream, (const float4*)table, (uint2*)bt, nPairs);

        hipLaunchKernelGGL(ingp_encode_bf, dim3(NLVL * chunksPerLevel), dim3(256),
                           0, stream, (const float4*)x, bt, feat,
                           N, chunksPerLevel, res);

        hipLaunchKernelGGL(ingp_mlp, dim3((N + 255) / 256), dim3(256), 0, stream,
                           feat, w0, w1, w2, wout, bout, out, N);
    } else if (ws_size >= featBytes) {
        float2* feat = (float2*)d_ws;
        hipLaunchKernelGGL(ingp_encode, dim3(NLVL * chunksPerLevel), dim3(256),
                           0, stream, (const float4*)x, (const float2*)table, feat,
                           N, chunksPerLevel, res);
        hipLaunchKernelGGL(ingp_mlp, dim3((N + 255) / 256), dim3(256), 0, stream,
                           feat, w0, w1, w2, wout, bout, out, N);
    } else {
        hipLaunchKernelGGL(ingp_fused, dim3((N + 255) / 256), dim3(256), 0, stream,
                           (const float4*)x, (const float2*)table,
                           w0, w1, w2, wout, bout, out, N, res);
    }
}

// Round 8
// 958.030 us; speedup vs baseline: 2.4826x; 1.5105x over previous
//
#include <hip/hip_runtime.h>
#include <math.h>

#define NLVL  16
#define TSZ   (1u << 19)
#define TMASK (TSZ - 1u)

struct ResArr { int m1[NLVL * 4]; };  // per level, per dim: res-1

typedef short  short8  __attribute__((ext_vector_type(8)));
typedef float  float4v __attribute__((ext_vector_type(4)));

static __device__ __forceinline__ unsigned short f2bf(float f) {
    unsigned u = __float_as_uint(f);
    return (unsigned short)((u + 0x7fffu + ((u >> 16) & 1u)) >> 16);  // RNE
}

// ---------------------------------------------------------------------------
// Encode: EXACT round-4 structure (830 us, the best measured; L2-request-rate
// bound at ~1.9 cyc/lane-req — rounds 5 & 7 proved both wider (16 B) and
// narrower (4 B) gathers regress). Only change: the feature store packs the
// two fp32 features to bf16 in one dword (halves feat traffic; the packed
// dword is directly the MFMA A-fragment register for the MLP).
// ---------------------------------------------------------------------------
__global__ __launch_bounds__(256, 4)
void ingp_encode(const float4* __restrict__ x,
                 const float2* __restrict__ table,
                 unsigned*     __restrict__ featbf,  // [NLVL][N] bf16 pairs
                 int N, int chunksPerLevel, ResArr res)
{
    const int l     = blockIdx.x / chunksPerLevel;
    const int chunk = blockIdx.x - l * chunksPerLevel;
    const int n     = chunk * 256 + threadIdx.x;
    if (n >= N) return;

    const float4 xv = x[n];
    const float px[4] = {xv.x, xv.y, xv.z, xv.w};

    int   rm[4], bi[4];
    float fr[4], om[4];
    #pragma unroll
    for (int d = 0; d < 4; ++d) {
        const int r = res.m1[l * 4 + d];       // wave-uniform -> scalar
        rm[d] = r;
        const float pos = px[d] * (float)r;
        const float fb  = floorf(pos);
        fr[d] = pos - fb;
        om[d] = 1.0f - fr[d];
        bi[d] = (int)fb;
    }
    const float2* tl = table + (size_t)l * TSZ;

    float2 fv[16];
    float  wt[16];
    #pragma unroll
    for (int c = 0; c < 16; ++c) {
        int c0 = bi[0] + ( c       & 1);
        int c1 = bi[1] + ((c >> 1) & 1);
        int c2 = bi[2] + ((c >> 2) & 1);
        int c3 = bi[3] + ((c >> 3) & 1);
        c0 = min(max(c0, 0), rm[0]);
        c1 = min(max(c1, 0), rm[1]);
        c2 = min(max(c2, 0), rm[2]);
        c3 = min(max(c3, 0), rm[3]);
        const unsigned hh = (unsigned)c0
                          ^ ((unsigned)c1 * 2654435761u)
                          ^ ((unsigned)c2 * 805459861u)
                          ^ ((unsigned)c3 * 3674653429u);
        fv[c] = tl[hh & TMASK];
        float w = ( c       & 1) ? fr[0] : om[0];
        w      *= ((c >> 1) & 1) ? fr[1] : om[1];
        w      *= ((c >> 2) & 1) ? fr[2] : om[2];
        w      *= ((c >> 3) & 1) ? fr[3] : om[3];
        wt[c] = w;
    }

    float a0 = 0.0f, a1 = 0.0f;
    #pragma unroll
    for (int c = 0; c < 16; ++c) {           // same order as reference einsum
        a0 = fmaf(wt[c], fv[c].x, a0);
        a1 = fmaf(wt[c], fv[c].y, a1);
    }
    featbf[(size_t)l * N + n] = (unsigned)f2bf(a0) | ((unsigned)f2bf(a1) << 16);
}

// ---------------------------------------------------------------------------
// MFMA MLP. Wave-tile = 16 points. mfma_f32_16x16x32_bf16:
//   A[m=lane&15][k=(lane>>4)*8+j]  (guide-verified, m118/m120)
//   B[k=(lane>>4)*8+j][n=lane&15]
//   D col=lane&15, row=(lane>>4)*4+reg (guide-verified, m89/m91)
// Weights bf16-rounded into 22 register fragments, loaded once per wave and
// reused over tilesPerWave tiles. Between layers the activations round-trip
// through LDS (row pad 144 B -> b128 reads are 2-way-conflict = free).
// ---------------------------------------------------------------------------
__global__ __launch_bounds__(256, 2)
void ingp_mlp_mfma(const unsigned* __restrict__ featbf,  // [NLVL][N]
                   const float*    __restrict__ w0,
                   const float*    __restrict__ w1,
                   const float*    __restrict__ w2,
                   const float*    __restrict__ wout,
                   const float*    __restrict__ bout,
                   float*          __restrict__ out,
                   int N, int tilesPerWave)
{
    __shared__ char lds_raw[4 * 16 * 144];
    const int tid  = threadIdx.x;
    const int wave = tid >> 6;
    const int lane = tid & 63;
    const int q    = lane >> 4;     // quad: K-chunk selector
    const int nn   = lane & 15;     // neuron / point within tile
    char* hbase = lds_raw + wave * (16 * 144);

    // ---- weight fragments (once per wave) ----
    short8 w0f[4];                  // layer0: 4 N-tiles, K=32 (1 step)
    #pragma unroll
    for (int t = 0; t < 4; ++t) {
        const float* wr = w0 + (t * 16 + nn) * 32 + q * 8;
        #pragma unroll
        for (int e = 0; e < 8; ++e) w0f[t][e] = (short)f2bf(wr[e]);
    }
    short8 w1f[2][4], w2f[2][4];    // layers1/2: K=64 (2 steps) x 4 N-tiles
    #pragma unroll
    for (int s = 0; s < 2; ++s) {
        #pragma unroll
        for (int t = 0; t < 4; ++t) {
            const float* wr1 = w1 + (t * 16 + nn) * 64 + s * 32 + q * 8;
            const float* wr2 = w2 + (t * 16 + nn) * 64 + s * 32 + q * 8;
            #pragma unroll
            for (int e = 0; e < 8; ++e) {
                w1f[s][t][e] = (short)f2bf(wr1[e]);
                w2f[s][t][e] = (short)f2bf(wr2[e]);
            }
        }
    }
    short8 wof[2];                  // out layer: N=16 (3 valid), K=64
    #pragma unroll
    for (int s = 0; s < 2; ++s) {
        #pragma unroll
        for (int e = 0; e < 8; ++e) {
            wof[s][e] = (nn < 3) ? (short)f2bf(wout[nn * 64 + s * 32 + q * 8 + e])
                                 : (short)0;
        }
    }
    const float bias = (nn < 3) ? bout[nn] : 0.0f;

    const int waveId = blockIdx.x * 4 + wave;

    for (int it = 0; it < tilesPerWave; ++it) {
        const int p0 = (waveId * tilesPerWave + it) * 16;
        if (p0 >= N) break;
        const int p = p0 + nn;

        // ---- layer 0: A from packed bf16 features (dword v = level q*4+v) --
        short8 a0;
        #pragma unroll
        for (int v = 0; v < 4; ++v) {
            const unsigned u = featbf[(size_t)(q * 4 + v) * N + p];
            a0[2 * v]     = (short)(u & 0xffffu);
            a0[2 * v + 1] = (short)(u >> 16);
        }
        float4v acc0[4];
        #pragma unroll
        for (int t = 0; t < 4; ++t) {
            acc0[t] = (float4v){0.f, 0.f, 0.f, 0.f};
            acc0[t] = __builtin_amdgcn_mfma_f32_16x16x32_bf16(a0, w0f[t], acc0[t], 0, 0, 0);
        }
        #pragma unroll
        for (int t = 0; t < 4; ++t)
            #pragma unroll
            for (int r = 0; r < 4; ++r)
                *(unsigned short*)(hbase + (q * 4 + r) * 144 + (t * 16 + nn) * 2) =
                    f2bf(fmaxf(acc0[t][r], 0.0f));

        // ---- layer 1 ----
        short8 a1[2];
        #pragma unroll
        for (int s = 0; s < 2; ++s)
            a1[s] = *(const short8*)(hbase + nn * 144 + s * 64 + q * 16);
        float4v acc1[4];
        #pragma unroll
        for (int t = 0; t < 4; ++t) {
            acc1[t] = (float4v){0.f, 0.f, 0.f, 0.f};
            #pragma unroll
            for (int s = 0; s < 2; ++s)
                acc1[t] = __builtin_amdgcn_mfma_f32_16x16x32_bf16(a1[s], w1f[s][t], acc1[t], 0, 0, 0);
        }
        #pragma unroll
        for (int t = 0; t < 4; ++t)
            #pragma unroll
            for (int r = 0; r < 4; ++r)
                *(unsigned short*)(hbase + (q * 4 + r) * 144 + (t * 16 + nn) * 2) =
                    f2bf(fmaxf(acc1[t][r], 0.0f));

        // ---- layer 2 ----
        short8 a2[2];
        #pragma unroll
        for (int s = 0; s < 2; ++s)
            a2[s] = *(const short8*)(hbase + nn * 144 + s * 64 + q * 16);
        float4v acc2[4];
        #pragma unroll
        for (int t = 0; t < 4; ++t) {
            acc2[t] = (float4v){0.f, 0.f, 0.f, 0.f};
            #pragma unroll
            for (int s = 0; s < 2; ++s)
                acc2[t] = __builtin_amdgcn_mfma_f32_16x16x32_bf16(a2[s], w2f[s][t], acc2[t], 0, 0, 0);
        }
        #pragma unroll
        for (int t = 0; t < 4; ++t)
            #pragma unroll
            for (int r = 0; r < 4; ++r)
                *(unsigned short*)(hbase + (q * 4 + r) * 144 + (t * 16 + nn) * 2) =
                    f2bf(fmaxf(acc2[t][r], 0.0f));

        // ---- output layer (3 valid cols) ----
        short8 a3[2];
        #pragma unroll
        for (int s = 0; s < 2; ++s)
            a3[s] = *(const short8*)(hbase + nn * 144 + s * 64 + q * 16);
        float4v oc = (float4v){0.f, 0.f, 0.f, 0.f};
        #pragma unroll
        for (int s = 0; s < 2; ++s)
            oc = __builtin_amdgcn_mfma_f32_16x16x32_bf16(a3[s], wof[s], oc, 0, 0, 0);

        if (nn < 3) {
            #pragma unroll
            for (int r = 0; r < 4; ++r) {
                const int pt = p0 + q * 4 + r;
                if (pt < N) out[pt * 3 + nn] = oc[r] + bias;
            }
        }
    }
}

// ---------------------------------------------------------------------------
// Fallback: round-2 fused kernel (used only if ws is too small for features).
// ---------------------------------------------------------------------------
__global__ __launch_bounds__(256, 2)
void ingp_fused(const float4* __restrict__ x,
                const float2* __restrict__ table,
                const float*  __restrict__ w0,
                const float*  __restrict__ w1,
                const float*  __restrict__ w2,
                const float*  __restrict__ wout,
                const float*  __restrict__ bout,
                float*        __restrict__ out,
                int N, ResArr res)
{
    const int n = blockIdx.x * blockDim.x + threadIdx.x;
    if (n >= N) return;

    const float4 xv = x[n];
    const float px[4] = {xv.x, xv.y, xv.z, xv.w};

    float h1[64];
    #pragma unroll
    for (int j = 0; j < 64; ++j) h1[j] = 0.0f;

    float a0p = 0.0f, a1p = 0.0f;

    #pragma unroll 1
    for (int l = 0; l < NLVL; ++l) {
        int   rm[4], bi[4];
        float fr[4], om[4];
        #pragma unroll
        for (int d = 0; d < 4; ++d) {
            const int r = res.m1[l * 4 + d];
            rm[d] = r;
            const float pos = px[d] * (float)r;
            const float fb  = floorf(pos);
            fr[d] = pos - fb;
            om[d] = 1.0f - fr[d];
            bi[d] = (int)fb;
        }
        const float2* tl = table + (size_t)l * TSZ;

        float2 fv[16];
        float  wt[16];
        #pragma unroll
        for (int c = 0; c < 16; ++c) {
            int c0 = bi[0] + ( c       & 1);
            int c1 = bi[1] + ((c >> 1) & 1);
            int c2 = bi[2] + ((c >> 2) & 1);
            int c3 = bi[3] + ((c >> 3) & 1);
            c0 = min(max(c0, 0), rm[0]);
            c1 = min(max(c1, 0), rm[1]);
            c2 = min(max(c2, 0), rm[2]);
            c3 = min(max(c3, 0), rm[3]);
            const unsigned hh = (unsigned)c0
                              ^ ((unsigned)c1 * 2654435761u)
                              ^ ((unsigned)c2 * 805459861u)
                              ^ ((unsigned)c3 * 3674653429u);
            fv[c] = tl[hh & TMASK];
            float w = ( c       & 1) ? fr[0] : om[0];
            w      *= ((c >> 1) & 1) ? fr[1] : om[1];
            w      *= ((c >> 2) & 1) ? fr[2] : om[2];
            w      *= ((c >> 3) & 1) ? fr[3] : om[3];
            wt[c] = w;
        }
        {
            const int lp = (l == 0) ? 0 : (l - 1);
            const float* w0c = w0 + 2 * lp;
            #pragma unroll
            for (int j = 0; j < 64; ++j)
                h1[j] = fmaf(w0c[j * 32], a0p, fmaf(w0c[j * 32 + 1], a1p, h1[j]));
        }
        float a0 = 0.0f, a1 = 0.0f;
        #pragma unroll
        for (int c = 0; c < 16; ++c) {
            a0 = fmaf(wt[c], fv[c].x, a0);
            a1 = fmaf(wt[c], fv[c].y, a1);
        }
        a0p = a0; a1p = a1;
    }
    {
        const float* w0c = w0 + 2 * (NLVL - 1);
        #pragma unroll
        for (int j = 0; j < 64; ++j)
            h1[j] = fmaf(w0c[j * 32], a0p, fmaf(w0c[j * 32 + 1], a1p, h1[j]));
    }
    #pragma unroll
    for (int j = 0; j < 64; ++j) h1[j] = fmaxf(h1[j], 0.0f);

    float h2[64];
    #pragma unroll
    for (int j = 0; j < 64; ++j) {
        float acc = 0.0f;
        const float* wr = w1 + j * 64;
        #pragma unroll
        for (int i = 0; i < 64; ++i) acc = fmaf(wr[i], h1[i], acc);
        h2[j] = fmaxf(acc, 0.0f);
    }
    float h3[64];
    #pragma unroll
    for (int j = 0; j < 64; ++j) {
        float acc = 0.0f;
        const float* wr = w2 + j * 64;
        #pragma unroll
        for (int i = 0; i < 64; ++i) acc = fmaf(wr[i], h2[i], acc);
        h3[j] = fmaxf(acc, 0.0f);
    }
    float o[3];
    #pragma unroll
    for (int k = 0; k < 3; ++k) {
        float acc = bout[k];
        const float* wr = wout + k * 64;
        #pragma unroll
        for (int i = 0; i < 64; ++i) acc = fmaf(wr[i], h3[i], acc);
        o[k] = acc;
    }
    out[n * 3 + 0] = o[0];
    out[n * 3 + 1] = o[1];
    out[n * 3 + 2] = o[2];
}

extern "C" void kernel_launch(void* const* d_in, const int* in_sizes, int n_in,
                              void* d_out, int out_size, void* d_ws, size_t ws_size,
                              hipStream_t stream) {
    (void)n_in; (void)out_size;

    const float* x     = (const float*)d_in[0];
    const float* table = (const float*)d_in[1];
    const float* w0    = (const float*)d_in[2];
    const float* w1    = (const float*)d_in[3];
    const float* w2    = (const float*)d_in[4];
    const float* wout  = (const float*)d_in[5];
    const float* bout  = (const float*)d_in[6];
    float* out = (float*)d_out;

    const int N = in_sizes[0] / 4;

    // Replicate numpy's float64 resolution computation bit-for-bit (same
    // glibc pow). Levels 5/10/15 of dim 3 sit on exact integer boundaries
    // (8^(5/15)==2), so floor() must see the same double as numpy produced.
    ResArr res;
    for (int d = 0; d < 4; ++d) {
        const double minr = 16.0;
        const double maxr = (d == 3) ? 128.0 : 256.0;
        const double growth = pow(maxr / minr, 1.0 / (double)(NLVL - 1));
        for (int l = 0; l < NLVL; ++l) {
            const int r = (int)floor(minr * pow(growth, (double)l));
            res.m1[l * 4 + d] = r - 1;
        }
    }

    const size_t featBytes = (size_t)NLVL * (size_t)N * sizeof(unsigned);
    const int chunksPerLevel = (N + 255) / 256;

    if (ws_size >= featBytes) {
        unsigned* featbf = (unsigned*)d_ws;
        hipLaunchKernelGGL(ingp_encode, dim3(NLVL * chunksPerLevel), dim3(256),
                           0, stream, (const float4*)x, (const float2*)table,
                           featbf, N, chunksPerLevel, res);

        const int tilesPerWave = 8;
        const int tiles  = (N + 15) / 16;
        const int waves  = (tiles + tilesPerWave - 1) / tilesPerWave;
        const int blocks = (waves + 3) / 4;
        hipLaunchKernelGGL(ingp_mlp_mfma, dim3(blocks), dim3(256), 0, stream,
                           featbf, w0, w1, w2, wout, bout, out, N, tilesPerWave);
    } else {
        hipLaunchKernelGGL(ingp_fused, dim3((N + 255) / 256), dim3(256), 0, stream,
                           (const float4*)x, (const float2*)table,
                           w0, w1, w2, wout, bout, out, N, res);
    }
}

// Round 9
// 838.984 us; speedup vs baseline: 2.8349x; 1.1419x over previous
//
#include <hip/hip_runtime.h>
#include <math.h>

#define NLVL  16
#define TSZ   (1u << 19)
#define TMASK (TSZ - 1u)

struct ResArr { int m1[NLVL * 4]; };  // per level, per dim: res-1

typedef short  short8  __attribute__((ext_vector_type(8)));
typedef float  float4v __attribute__((ext_vector_type(4)));

static __device__ __forceinline__ unsigned short f2bf(float f) {
    unsigned u = __float_as_uint(f);
    return (unsigned short)((u + 0x7fffu + ((u >> 16) & 1u)) >> 16);  // RNE
}

// ---------------------------------------------------------------------------
// Encode: round-8 structure (789 us, L2-request-rate bound: ~17.7 req/cy/XCD
// vs ~16 channels). New: divergent corner-pair loads. PRIMES[0]==1 => corners
// (bi0, bi0+1) hash to {h, h^1}; when bi0 is EVEN these are an aligned float4
// -> 8x16B loads instead of 16x8B. Odd bi0 keeps 16x8B. Measured width costs
// (8B=1.9, 16B=2.5 cyc/req) => expected avg -17% request-equivalents.
// Clamps never bind (pos = x*(res-1) < res-1 strictly, incl. fp32 rounding
// edge at power-of-2 res) so adjacency always holds; dropped -> bit-exact.
// Feature store packs bf16 pairs (round-8; feeds MFMA MLP directly).
// ---------------------------------------------------------------------------
__global__ __launch_bounds__(256, 4)
void ingp_encode(const float4* __restrict__ x,
                 const float2* __restrict__ table,
                 unsigned*     __restrict__ featbf,  // [NLVL][N] bf16 pairs
                 int N, int chunksPerLevel, ResArr res)
{
    const int l     = blockIdx.x / chunksPerLevel;
    const int chunk = blockIdx.x - l * chunksPerLevel;
    const int n     = chunk * 256 + threadIdx.x;
    if (n >= N) return;

    const float4 xv = x[n];
    const float px[4] = {xv.x, xv.y, xv.z, xv.w};

    int   bi[4];
    float fr[4], om[4];
    #pragma unroll
    for (int d = 0; d < 4; ++d) {
        const int r = res.m1[l * 4 + d];       // wave-uniform -> scalar
        const float pos = px[d] * (float)r;
        const float fb  = floorf(pos);
        fr[d] = pos - fb;
        om[d] = 1.0f - fr[d];
        bi[d] = (int)fb;
    }
    const float2* tl  = table + (size_t)l * TSZ;
    const float4* tl4 = (const float4*)tl;

    // hashes of the 8 (dim1,dim2,dim3) corner combos, shared by both arms
    unsigned hrest[8];
    #pragma unroll
    for (int p = 0; p < 8; ++p) {
        const int c1 = bi[1] + ( p       & 1);
        const int c2 = bi[2] + ((p >> 1) & 1);
        const int c3 = bi[3] + ((p >> 2) & 1);
        hrest[p] = ((unsigned)c1 * 2654435761u)
                 ^ ((unsigned)c2 * 805459861u)
                 ^ ((unsigned)c3 * 3674653429u);
    }

    float2 fv[16];   // fv[2p] = dim0-offset 0, fv[2p+1] = dim0-offset 1
    if ((bi[0] & 1) == 0) {
        // even: pair (h, h^1) lives in one aligned float4 at index h>>1
        #pragma unroll
        for (int p = 0; p < 8; ++p) {
            const unsigned h = ((unsigned)bi[0] ^ hrest[p]) & TMASK;
            const float4 q = tl4[h >> 1];
            const bool odd = (h & 1);
            fv[2 * p]     = odd ? make_float2(q.z, q.w) : make_float2(q.x, q.y);
            fv[2 * p + 1] = odd ? make_float2(q.x, q.y) : make_float2(q.z, q.w);
        }
    } else {
        #pragma unroll
        for (int p = 0; p < 8; ++p) {
            const unsigned hA = ((unsigned)bi[0]       ^ hrest[p]) & TMASK;
            const unsigned hB = ((unsigned)(bi[0] + 1) ^ hrest[p]) & TMASK;
            fv[2 * p]     = tl[hA];
            fv[2 * p + 1] = tl[hB];
        }
    }

    float wt[16];
    #pragma unroll
    for (int c = 0; c < 16; ++c) {           // identical formula/order to r8
        float w = ( c       & 1) ? fr[0] : om[0];
        w      *= ((c >> 1) & 1) ? fr[1] : om[1];
        w      *= ((c >> 2) & 1) ? fr[2] : om[2];
        w      *= ((c >> 3) & 1) ? fr[3] : om[3];
        wt[c] = w;
    }

    float a0 = 0.0f, a1 = 0.0f;
    #pragma unroll
    for (int c = 0; c < 16; ++c) {           // same order as reference einsum
        a0 = fmaf(wt[c], fv[c].x, a0);
        a1 = fmaf(wt[c], fv[c].y, a1);
    }
    featbf[(size_t)l * N + n] = (unsigned)f2bf(a0) | ((unsigned)f2bf(a1) << 16);
}

// ---------------------------------------------------------------------------
// MFMA MLP — EXACT round-8 kernel (~165 us, absmax 0.0). Wave-tile = 16 pts;
// weights bf16 in 22 register fragments loaded once per wave; activations
// round-trip LDS (144 B row pad -> b128 reads 2-way = free).
// ---------------------------------------------------------------------------
__global__ __launch_bounds__(256, 2)
void ingp_mlp_mfma(const unsigned* __restrict__ featbf,  // [NLVL][N]
                   const float*    __restrict__ w0,
                   const float*    __restrict__ w1,
                   const float*    __restrict__ w2,
                   const float*    __restrict__ wout,
                   const float*    __restrict__ bout,
                   float*          __restrict__ out,
                   int N, int tilesPerWave)
{
    __shared__ char lds_raw[4 * 16 * 144];
    const int tid  = threadIdx.x;
    const int wave = tid >> 6;
    const int lane = tid & 63;
    const int q    = lane >> 4;     // quad: K-chunk selector
    const int nn   = lane & 15;     // neuron / point within tile
    char* hbase = lds_raw + wave * (16 * 144);

    short8 w0f[4];
    #pragma unroll
    for (int t = 0; t < 4; ++t) {
        const float* wr = w0 + (t * 16 + nn) * 32 + q * 8;
        #pragma unroll
        for (int e = 0; e < 8; ++e) w0f[t][e] = (short)f2bf(wr[e]);
    }
    short8 w1f[2][4], w2f[2][4];
    #pragma unroll
    for (int s = 0; s < 2; ++s) {
        #pragma unroll
        for (int t = 0; t < 4; ++t) {
            const float* wr1 = w1 + (t * 16 + nn) * 64 + s * 32 + q * 8;
            const float* wr2 = w2 + (t * 16 + nn) * 64 + s * 32 + q * 8;
            #pragma unroll
            for (int e = 0; e < 8; ++e) {
                w1f[s][t][e] = (short)f2bf(wr1[e]);
                w2f[s][t][e] = (short)f2bf(wr2[e]);
            }
        }
    }
    short8 wof[2];
    #pragma unroll
    for (int s = 0; s < 2; ++s) {
        #pragma unroll
        for (int e = 0; e < 8; ++e) {
            wof[s][e] = (nn < 3) ? (short)f2bf(wout[nn * 64 + s * 32 + q * 8 + e])
                                 : (short)0;
        }
    }
    const float bias = (nn < 3) ? bout[nn] : 0.0f;

    const int waveId = blockIdx.x * 4 + wave;

    for (int it = 0; it < tilesPerWave; ++it) {
        const int p0 = (waveId * tilesPerWave + it) * 16;
        if (p0 >= N) break;
        const int p = p0 + nn;

        short8 a0;
        #pragma unroll
        for (int v = 0; v < 4; ++v) {
            const unsigned u = featbf[(size_t)(q * 4 + v) * N + p];
            a0[2 * v]     = (short)(u & 0xffffu);
            a0[2 * v + 1] = (short)(u >> 16);
        }
        float4v acc0[4];
        #pragma unroll
        for (int t = 0; t < 4; ++t) {
            acc0[t] = (float4v){0.f, 0.f, 0.f, 0.f};
            acc0[t] = __builtin_amdgcn_mfma_f32_16x16x32_bf16(a0, w0f[t], acc0[t], 0, 0, 0);
        }
        #pragma unroll
        for (int t = 0; t < 4; ++t)
            #pragma unroll
            for (int r = 0; r < 4; ++r)
                *(unsigned short*)(hbase + (q * 4 + r) * 144 + (t * 16 + nn) * 2) =
                    f2bf(fmaxf(acc0[t][r], 0.0f));

        short8 a1[2];
        #pragma unroll
        for (int s = 0; s < 2; ++s)
            a1[s] = *(const short8*)(hbase + nn * 144 + s * 64 + q * 16);
        float4v acc1[4];
        #pragma unroll
        for (int t = 0; t < 4; ++t) {
            acc1[t] = (float4v){0.f, 0.f, 0.f, 0.f};
            #pragma unroll
            for (int s = 0; s < 2; ++s)
                acc1[t] = __builtin_amdgcn_mfma_f32_16x16x32_bf16(a1[s], w1f[s][t], acc1[t], 0, 0, 0);
        }
        #pragma unroll
        for (int t = 0; t < 4; ++t)
            #pragma unroll
            for (int r = 0; r < 4; ++r)
                *(unsigned short*)(hbase + (q * 4 + r) * 144 + (t * 16 + nn) * 2) =
                    f2bf(fmaxf(acc1[t][r], 0.0f));

        short8 a2[2];
        #pragma unroll
        for (int s = 0; s < 2; ++s)
            a2[s] = *(const short8*)(hbase + nn * 144 + s * 64 + q * 16);
        float4v acc2[4];
        #pragma unroll
        for (int t = 0; t < 4; ++t) {
            acc2[t] = (float4v){0.f, 0.f, 0.f, 0.f};
            #pragma unroll
            for (int s = 0; s < 2; ++s)
                acc2[t] = __builtin_amdgcn_mfma_f32_16x16x32_bf16(a2[s], w2f[s][t], acc2[t], 0, 0, 0);
        }
        #pragma unroll
        for (int t = 0; t < 4; ++t)
            #pragma unroll
            for (int r = 0; r < 4; ++r)
                *(unsigned short*)(hbase + (q * 4 + r) * 144 + (t * 16 + nn) * 2) =
                    f2bf(fmaxf(acc2[t][r], 0.0f));

        short8 a3[2];
        #pragma unroll
        for (int s = 0; s < 2; ++s)
            a3[s] = *(const short8*)(hbase + nn * 144 + s * 64 + q * 16);
        float4v oc = (float4v){0.f, 0.f, 0.f, 0.f};
        #pragma unroll
        for (int s = 0; s < 2; ++s)
            oc = __builtin_amdgcn_mfma_f32_16x16x32_bf16(a3[s], wof[s], oc, 0, 0, 0);

        if (nn < 3) {
            #pragma unroll
            for (int r = 0; r < 4; ++r) {
                const int pt = p0 + q * 4 + r;
                if (pt < N) out[pt * 3 + nn] = oc[r] + bias;
            }
        }
    }
}

// ---------------------------------------------------------------------------
// Fallback: round-2 fused kernel (used only if ws is too small for features).
// ---------------------------------------------------------------------------
__global__ __launch_bounds__(256, 2)
void ingp_fused(const float4* __restrict__ x,
                const float2* __restrict__ table,
                const float*  __restrict__ w0,
                const float*  __restrict__ w1,
                const float*  __restrict__ w2,
                const float*  __restrict__ wout,
                const float*  __restrict__ bout,
                float*        __restrict__ out,
                int N, ResArr res)
{
    const int n = blockIdx.x * blockDim.x + threadIdx.x;
    if (n >= N) return;

    const float4 xv = x[n];
    const float px[4] = {xv.x, xv.y, xv.z, xv.w};

    float h1[64];
    #pragma unroll
    for (int j = 0; j < 64; ++j) h1[j] = 0.0f;

    float a0p = 0.0f, a1p = 0.0f;

    #pragma unroll 1
    for (int l = 0; l < NLVL; ++l) {
        int   rm[4], bi[4];
        float fr[4], om[4];
        #pragma unroll
        for (int d = 0; d < 4; ++d) {
            const int r = res.m1[l * 4 + d];
            rm[d] = r;
            const float pos = px[d] * (float)r;
            const float fb  = floorf(pos);
            fr[d] = pos - fb;
            om[d] = 1.0f - fr[d];
            bi[d] = (int)fb;
        }
        const float2* tl = table + (size_t)l * TSZ;

        float2 fv[16];
        float  wt[16];
        #pragma unroll
        for (int c = 0; c < 16; ++c) {
            int c0 = bi[0] + ( c       & 1);
            int c1 = bi[1] + ((c >> 1) & 1);
            int c2 = bi[2] + ((c >> 2) & 1);
            int c3 = bi[3] + ((c >> 3) & 1);
            c0 = min(max(c0, 0), rm[0]);
            c1 = min(max(c1, 0), rm[1]);
            c2 = min(max(c2, 0), rm[2]);
            c3 = min(max(c3, 0), rm[3]);
            const unsigned hh = (unsigned)c0
                              ^ ((unsigned)c1 * 2654435761u)
                              ^ ((unsigned)c2 * 805459861u)
                              ^ ((unsigned)c3 * 3674653429u);
            fv[c] = tl[hh & TMASK];
            float w = ( c       & 1) ? fr[0] : om[0];
            w      *= ((c >> 1) & 1) ? fr[1] : om[1];
            w      *= ((c >> 2) & 1) ? fr[2] : om[2];
            w      *= ((c >> 3) & 1) ? fr[3] : om[3];
            wt[c] = w;
        }
        {
            const int lp = (l == 0) ? 0 : (l - 1);
            const float* w0c = w0 + 2 * lp;
            #pragma unroll
            for (int j = 0; j < 64; ++j)
                h1[j] = fmaf(w0c[j * 32], a0p, fmaf(w0c[j * 32 + 1], a1p, h1[j]));
        }
        float a0 = 0.0f, a1 = 0.0f;
        #pragma unroll
        for (int c = 0; c < 16; ++c) {
            a0 = fmaf(wt[c], fv[c].x, a0);
            a1 = fmaf(wt[c], fv[c].y, a1);
        }
        a0p = a0; a1p = a1;
    }
    {
        const float* w0c = w0 + 2 * (NLVL - 1);
        #pragma unroll
        for (int j = 0; j < 64; ++j)
            h1[j] = fmaf(w0c[j * 32], a0p, fmaf(w0c[j * 32 + 1], a1p, h1[j]));
    }
    #pragma unroll
    for (int j = 0; j < 64; ++j) h1[j] = fmaxf(h1[j], 0.0f);

    float h2[64];
    #pragma unroll
    for (int j = 0; j < 64; ++j) {
        float acc = 0.0f;
        const float* wr = w1 + j * 64;
        #pragma unroll
        for (int i = 0; i < 64; ++i) acc = fmaf(wr[i], h1[i], acc);
        h2[j] = fmaxf(acc, 0.0f);
    }
    float h3[64];
    #pragma unroll
    for (int j = 0; j < 64; ++j) {
        float acc = 0.0f;
        const float* wr = w2 + j * 64;
        #pragma unroll
        for (int i = 0; i < 64; ++i) acc = fmaf(wr[i], h2[i], acc);
        h3[j] = fmaxf(acc, 0.0f);
    }
    float o[3];
    #pragma unroll
    for (int k = 0; k < 3; ++k) {
        float acc = bout[k];
        const float* wr = wout + k * 64;
        #pragma unroll
        for (int i = 0; i < 64; ++i) acc = fmaf(wr[i], h3[i], acc);
        o[k] = acc;
    }
    out[n * 3 + 0] = o[0];
    out[n * 3 + 1] = o[1];
    out[n * 3 + 2] = o[2];
}

extern "C" void kernel_launch(void* const* d_in, const int* in_sizes, int n_in,
                              void* d_out, int out_size, void* d_ws, size_t ws_size,
                              hipStream_t stream) {
    (void)n_in; (void)out_size;

    const float* x     = (const float*)d_in[0];
    const float* table = (const float*)d_in[1];
    const float* w0    = (const float*)d_in[2];
    const float* w1    = (const float*)d_in[3];
    const float* w2    = (const float*)d_in[4];
    const float* wout  = (const float*)d_in[5];
    const float* bout  = (const float*)d_in[6];
    float* out = (float*)d_out;

    const int N = in_sizes[0] / 4;

    // Replicate numpy's float64 resolution computation bit-for-bit (same
    // glibc pow). Levels 5/10/15 of dim 3 sit on exact integer boundaries
    // (8^(5/15)==2), so floor() must see the same double as numpy produced.
    ResArr res;
    for (int d = 0; d < 4; ++d) {
        const double minr = 16.0;
        const double maxr = (d == 3) ? 128.0 : 256.0;
        const double growth = pow(maxr / minr, 1.0 / (double)(NLVL - 1));
        for (int l = 0; l < NLVL; ++l) {
            const int r = (int)floor(minr * pow(growth, (double)l));
            res.m1[l * 4 + d] = r - 1;
        }
    }

    const size_t featBytes = (size_t)NLVL * (size_t)N * sizeof(unsigned);
    const int chunksPerLevel = (N + 255) / 256;

    if (ws_size >= featBytes) {
        unsigned* featbf = (unsigned*)d_ws;
        hipLaunchKernelGGL(ingp_encode, dim3(NLVL * chunksPerLevel), dim3(256),
                           0, stream, (const float4*)x, (const float2*)table,
                           featbf, N, chunksPerLevel, res);

        const int tilesPerWave = 8;
        const int tiles  = (N + 15) / 16;
        const int waves  = (tiles + tilesPerWave - 1) / tilesPerWave;
        const int blocks = (waves + 3) / 4;
        hipLaunchKernelGGL(ingp_mlp_mfma, dim3(blocks), dim3(256), 0, stream,
                           featbf, w0, w1, w2, wout, bout, out, N, tilesPerWave);
    } else {
        hipLaunchKernelGGL(ingp_fused, dim3((N + 255) / 256), dim3(256), 0, stream,
                           (const float4*)x, (const float2*)table,
                           w0, w1, w2, wout, bout, out, N, res);
    }
}